// Round 8
// baseline (15545.261 us; speedup 1.0000x reference)
//
#include <hip/hip_runtime.h>

#define HSZ 1024
#define TSTEPS 4096
#define NBLK 256
#define NTHR 256   // 4 waves/block x 256 blocks = 1024 waves == HSZ units
#define HV (HSZ / 4)
#define REP_BYTES 24576  // one replica: [2 parity][3 array][1024 tagged dwords]

typedef _Float16 half2v __attribute__((ext_vector_type(2)));
typedef unsigned long long ull;

#if __has_builtin(__builtin_amdgcn_fdot2)
#define FDOT2(a, b, c) __builtin_amdgcn_fdot2((a), (b), (c), false)
#else
__device__ __forceinline__ float FDOT2(half2v a, half2v b, float c) {
    return c + (float)a.x * (float)b.x + (float)a.y * (float)b.y;
}
#endif

__device__ __forceinline__ int f2i(float f) { int i; __builtin_memcpy(&i, &f, 4); return i; }
__device__ __forceinline__ float i2f(int i) { float f; __builtin_memcpy(&f, &i, 4); return f; }

// ---- DPP wave reduction: full 64-lane sum lands on lane 63 (VALU-rate) ----
template <int CTRL, int RM>
__device__ __forceinline__ float dpp_acc(float v) {
    int t = __builtin_amdgcn_update_dpp(0, f2i(v), CTRL, RM, 0xf, true);
    return v + i2f(t);
}
__device__ __forceinline__ float wave_sum63(float v) {
    v = dpp_acc<0x111, 0xf>(v);  // row_shr:1
    v = dpp_acc<0x112, 0xf>(v);  // row_shr:2
    v = dpp_acc<0x114, 0xf>(v);  // row_shr:4
    v = dpp_acc<0x118, 0xf>(v);  // row_shr:8  -> lane15/31/47/63 hold row sums
    v = dpp_acc<0x142, 0xa>(v);  // row_bcast:15 (rows 1,3 only)
    v = dpp_acc<0x143, 0xc>(v);  // row_bcast:31 (rows 2,3 only) -> lane63 = total
    return v;
}

__device__ __forceinline__ float sigm(float x) { return 1.0f / (1.0f + __expf(-x)); }
__device__ __forceinline__ float tanh_fast(float x) {
    const float e = __expf(2.0f * x);
    return 1.0f - 2.0f / (e + 1.0f);
}

// ---- agent-coherent (L3-level) accesses, no cache fences ----
__device__ __forceinline__ ull ld_coh64(const ull* p) {
    return __hip_atomic_load(p, __ATOMIC_RELAXED, __HIP_MEMORY_SCOPE_AGENT);
}
__device__ __forceinline__ void st_coh32(unsigned* p, unsigned v) {
    __hip_atomic_store(p, v, __ATOMIC_RELAXED, __HIP_MEMORY_SCOPE_AGENT);
}

__device__ __forceinline__ unsigned f16bits(float v) {
    _Float16 h = (_Float16)v;
    unsigned short b;
    __builtin_memcpy(&b, &h, 2);
    return (unsigned)b;
}

// Pin packed-f16 weight into a VGPR (prevents load re-sinking).
#define PINH(h) asm volatile("" : "+v"(h))

// f32->half2 (init path, RNE per element)
__device__ __forceinline__ half2v cvt2(float a, float b) {
    half2v r; r.x = (_Float16)a; r.y = (_Float16)b; return r;
}

__device__ __forceinline__ half2v bits_to_h2(unsigned v) {
    half2v h; __builtin_memcpy(&h, &v, 4); return h;
}

// strip two 16-bit tags from a tagged-dword pair -> packed f16 pair (1 v_perm)
__device__ __forceinline__ unsigned pack_payload(ull q) {
#if __has_builtin(__builtin_amdgcn_perm)
    return __builtin_amdgcn_perm((unsigned)(q >> 32), (unsigned)q, 0x05040100u);
#else
    return ((unsigned)q & 0xFFFFu) | ((unsigned)(q >> 32) << 16);
#endif
}

// ---- per-WAVE register-direct poll (champion geometry): 8 coalesced b64
// loads/lane cover one 1024-unit tagged array. Split-phase: issued one phase
// ahead, checked one phase later (flight hidden under compute). ----
struct PollA { ull q[8]; };

__device__ __forceinline__ PollA poll_issueA(const ull* A, int lane) {
    PollA p;
#pragma unroll
    for (int i = 0; i < 4; ++i) {
        p.q[2 * i]     = ld_coh64(A + 2 * lane + 128 * i);
        p.q[2 * i + 1] = ld_coh64(A + 2 * lane + 128 * i + 1);
    }
    return p;
}

// Selective-lane retry; retries 1-3 immediate (the marginal check that defines
// the period sits on this grid -- sleep wake-latency would add straight to T),
// sleep-backoff from the 4th retry to bound pathological congestion.
__device__ __forceinline__ void poll_completeA(PollA& p, const ull* A,
                                               unsigned e, int lane, half2v* hf) {
    const ull K = ((ull)e << 16) | ((ull)e << 48);
    ull bad = 0;
#pragma unroll
    for (int j = 0; j < 8; ++j) bad |= (p.q[j] ^ K);
    bad &= 0xFFFF0000FFFF0000ull;
    int tries = 0;
    while (!__all(bad == 0)) {
        if (tries >= 3) __builtin_amdgcn_s_sleep(2);
        ++tries;
        if (bad) {  // divergent: only stale lanes reload
#pragma unroll
            for (int i = 0; i < 4; ++i) {
                p.q[2 * i]     = ld_coh64(A + 2 * lane + 128 * i);
                p.q[2 * i + 1] = ld_coh64(A + 2 * lane + 128 * i + 1);
            }
            bad = 0;
#pragma unroll
            for (int j = 0; j < 8; ++j) bad |= (p.q[j] ^ K);
            bad &= 0xFFFF0000FFFF0000ull;
        }
    }
#pragma unroll
    for (int j = 0; j < 8; ++j) hf[j] = bits_to_h2(pack_payload(p.q[j]));
}

__global__ void __launch_bounds__(NTHR, 1) lstm_persist(
    const float* __restrict__ x,
    const float* __restrict__ Wih0, const float* __restrict__ Whh0,
    const float* __restrict__ bih0, const float* __restrict__ bhh0,
    const float* __restrict__ Wih12, const float* __restrict__ Whh12,
    const float* __restrict__ bih12, const float* __restrict__ bhh12,
    const float* __restrict__ Wres, const float* __restrict__ bres,
    float* __restrict__ out, float* __restrict__ ws_f, int nrep)
{
    char* wsb = (char*)ws_f;
    const int lane = threadIdx.x & 63;
    const int u = blockIdx.x * (NTHR / 64) + (threadIdx.x >> 6);  // hidden unit
    const int tid = threadIdx.x;

    // ---- init: parity 1 of every replica = tag 0, value 0 ----
    {
        const int gid = blockIdx.x * NTHR + tid;
        if (gid < nrep * 3072) {
            const int rep = gid / 3072, d = gid % 3072;
            st_coh32((unsigned*)(wsb + rep * REP_BYTES) + 3072 + d, 0u);
        }
    }

    // ---- per-wave scalar constants ----
    float b0[4], b1[4], b2[4], wx0a[4], wx0b[4];
#pragma unroll
    for (int g = 0; g < 4; ++g) {
        const int r = g * HSZ + u;
        b0[g] = bih0[r] + bhh0[r];
        b1[g] = bih12[r] + bhh12[r];
        b2[g] = bih12[4 * HSZ + r] + bhh12[4 * HSZ + r];
        wx0a[g] = Wih0[2 * r];
        wx0b[g] = Wih0[2 * r + 1];
    }

    // ---- register-resident f16 weights: 20 rows x 1024 -> 160 half2/lane ----
    const float4* Whh0v = (const float4*)Whh0;
    const float4* Wih1v = (const float4*)Wih12;
    const float4* Whh1v = (const float4*)Whh12;
    const float4* Wih2v = (const float4*)(Wih12 + 4 * HSZ * HSZ);
    const float4* Whh2v = (const float4*)(Whh12 + 4 * HSZ * HSZ);

    half2v w0h[4][8], wi1h[4][8], wh1h[4][8], wi2h[4][8], wh2h[4][8];
#pragma unroll
    for (int g = 0; g < 4; ++g) {
        const size_t r = (size_t)(g * HSZ + u) * HV + lane;
#pragma unroll
        for (int i = 0; i < 4; ++i) {
            float4 t;
            t = Whh0v[r + 64 * i];  w0h[g][2*i] = cvt2(t.x,t.y);  w0h[g][2*i+1] = cvt2(t.z,t.w);
            t = Wih1v[r + 64 * i];  wi1h[g][2*i] = cvt2(t.x,t.y); wi1h[g][2*i+1] = cvt2(t.z,t.w);
            t = Whh1v[r + 64 * i];  wh1h[g][2*i] = cvt2(t.x,t.y); wh1h[g][2*i+1] = cvt2(t.z,t.w);
            t = Wih2v[r + 64 * i];  wi2h[g][2*i] = cvt2(t.x,t.y); wi2h[g][2*i+1] = cvt2(t.z,t.w);
            t = Whh2v[r + 64 * i];  wh2h[g][2*i] = cvt2(t.x,t.y); wh2h[g][2*i+1] = cvt2(t.z,t.w);
        }
    }
#pragma unroll
    for (int g = 0; g < 4; ++g)
#pragma unroll
        for (int j = 0; j < 8; ++j) {
            PINH(w0h[g][j]); PINH(wi1h[g][j]); PINH(wh1h[g][j]);
            PINH(wi2h[g][j]); PINH(wh2h[g][j]);
        }

    // head weights as f16 (distributed head: every wave serves 4 of 4096 steps)
    half2v wresh[8];
    {
        const float4* wr = (const float4*)Wres;
#pragma unroll
        for (int i = 0; i < 4; ++i) {
            float4 t = wr[lane + 64 * i];
            wresh[2*i] = cvt2(t.x, t.y); wresh[2*i+1] = cvt2(t.z, t.w);
        }
    }
    const float bres0 = bres[0];

    // Drain init stores so no late init write can clobber a live tagged word.
    asm volatile("s_waitcnt vmcnt(0)" ::: "memory");
    __syncthreads();

    const ull* Tmyq = (const ull*)(wsb + (blockIdx.x % nrep) * REP_BYTES);

    float c0 = 0.0f, c1 = 0.0f, c2 = 0.0f;  // live on lane 63 only

    // Champion wavefront pipeline, split-phase polls (uniform slack geometry):
    //   iter k: check pq0 -> issue pq1 -> L0 -> pub h0
    //           -> check pq1 -> issue pq2 -> L1 -> pub h1
    //           -> check pq2 -> issue pq0(next parity) -> L2 -> pub h2 -> head?
    PollA pq0 = poll_issueA(Tmyq + 1536, lane);  // k=0 reads parity 1, array 0

    for (int k = 0; k <= TSTEPS + 2; ++k) {
        const int wp = k & 1, rp = wp ^ 1;
        const unsigned e = (unsigned)k;
        const ull* Trp = Tmyq + rp * 1536;
        const ull* Tnx = Tmyq + wp * 1536;  // next iter's read parity
        const bool pub = (k <= TSTEPS + 1);
        const unsigned tg = (unsigned)(k + 1) << 16;

        // prefetch x before the poll-wait (hides the load latency)
        float x0 = 0.0f, x1 = 0.0f;
        if (k < TSTEPS) { x0 = x[2 * k]; x1 = x[2 * k + 1]; }

        // ================= layer 0 =================
        half2v haf[8];
        poll_completeA(pq0, Trp, e, lane, haf);
        PollA pq1 = poll_issueA(Trp + 512, lane);  // in flight during L0

        float h0v = 0.0f;
        if (k < TSTEPS) {
            float acc[4];
#pragma unroll
            for (int g = 0; g < 4; ++g) {
                float a = 0.0f;
#pragma unroll
                for (int j = 0; j < 8; ++j) a = FDOT2(w0h[g][j], haf[j], a);
                acc[g] = a;
            }
#pragma unroll
            for (int g = 0; g < 4; ++g) acc[g] = wave_sum63(acc[g]);
            if (lane == 63) {
                const float ig = sigm(acc[0] + b0[0] + wx0a[0] * x0 + wx0b[0] * x1);
                const float fg = sigm(acc[1] + b0[1] + wx0a[1] * x0 + wx0b[1] * x1);
                const float gg = tanh_fast(acc[2] + b0[2] + wx0a[2] * x0 + wx0b[2] * x1);
                const float og = sigm(acc[3] + b0[3] + wx0a[3] * x0 + wx0b[3] * x1);
                c0 = fg * c0 + ig * gg;
                h0v = og * tanh_fast(c0);
            }
        }
        if (lane == 63 && pub) {
            const unsigned wb = tg | f16bits(h0v);
            for (int rep = 0; rep < nrep; ++rep)
                st_coh32((unsigned*)(wsb + rep * REP_BYTES) + wp * 3072 + u, wb);
        }

        // ================= layer 1 =================
        half2v hbf[8];
        poll_completeA(pq1, Trp + 512, e, lane, hbf);
        PollA pq2 = poll_issueA(Trp + 1024, lane);  // in flight during L1

        float h1v = 0.0f;
        if (k >= 1 && k <= TSTEPS) {
            float acc[4];
#pragma unroll
            for (int g = 0; g < 4; ++g) {
                float a = 0.0f;
#pragma unroll
                for (int j = 0; j < 8; ++j) {
                    a = FDOT2(wi1h[g][j], haf[j], a);
                    a = FDOT2(wh1h[g][j], hbf[j], a);
                }
                acc[g] = a;
            }
#pragma unroll
            for (int g = 0; g < 4; ++g) acc[g] = wave_sum63(acc[g]);
            if (lane == 63) {
                const float ig = sigm(acc[0] + b1[0]);
                const float fg = sigm(acc[1] + b1[1]);
                const float gg = tanh_fast(acc[2] + b1[2]);
                const float og = sigm(acc[3] + b1[3]);
                c1 = fg * c1 + ig * gg;
                h1v = og * tanh_fast(c1);
            }
        }
        if (lane == 63 && pub) {
            const unsigned wb = tg | f16bits(h1v);
            for (int rep = 0; rep < nrep; ++rep)
                st_coh32((unsigned*)(wsb + rep * REP_BYTES) + wp * 3072 + 1024 + u, wb);
        }

        // ================= layer 2 =================
        half2v hcf[8];
        poll_completeA(pq2, Trp + 1024, e, lane, hcf);
        pq0 = poll_issueA(Tnx, lane);  // next iter's array 0, in flight during L2

        float h2v = 0.0f;
        if (k >= 2 && k <= TSTEPS + 1) {
            float acc[4];
#pragma unroll
            for (int g = 0; g < 4; ++g) {
                float a = 0.0f;
#pragma unroll
                for (int j = 0; j < 8; ++j) {
                    a = FDOT2(wi2h[g][j], hbf[j], a);
                    a = FDOT2(wh2h[g][j], hcf[j], a);
                }
                acc[g] = a;
            }
#pragma unroll
            for (int g = 0; g < 4; ++g) acc[g] = wave_sum63(acc[g]);
            if (lane == 63) {
                const float ig = sigm(acc[0] + b2[0]);
                const float fg = sigm(acc[1] + b2[1]);
                const float gg = tanh_fast(acc[2] + b2[2]);
                const float og = sigm(acc[3] + b2[3]);
                c2 = fg * c2 + ig * gg;
                h2v = og * tanh_fast(c2);
            }
        }
        if (lane == 63 && pub) {
            const unsigned wb = tg | f16bits(h2v);
            for (int rep = 0; rep < nrep; ++rep)
                st_coh32((unsigned*)(wsb + rep * REP_BYTES) + wp * 3072 + 2048 + u, wb);
        }

        // ===== distributed head: out[t] served by wave t&1023 (4 per wave
        // total; wave-uniform branch, no permanent straggler) =====
        if (k >= 3 && ((k - 3) & (HSZ - 1)) == u) {
            float a = 0.0f;
#pragma unroll
            for (int j = 0; j < 8; ++j) a = FDOT2(wresh[j], hcf[j], a);
            a = wave_sum63(a);
            if (lane == 63) out[k - 3] = sigm(a + bres0);
        }
    }
}

extern "C" void kernel_launch(void* const* d_in, const int* in_sizes, int n_in,
                              void* d_out, int out_size, void* d_ws, size_t ws_size,
                              hipStream_t stream) {
    const float* x     = (const float*)d_in[0];
    const float* Wih0  = (const float*)d_in[1];
    const float* Whh0  = (const float*)d_in[2];
    const float* bih0  = (const float*)d_in[3];
    const float* bhh0  = (const float*)d_in[4];
    const float* Wih12 = (const float*)d_in[5];
    const float* Whh12 = (const float*)d_in[6];
    const float* bih12 = (const float*)d_in[7];
    const float* bhh12 = (const float*)d_in[8];
    const float* Wres  = (const float*)d_in[9];
    const float* bres  = (const float*)d_in[10];
    float* out = (float*)d_out;
    float* ws  = (float*)d_ws;

    // nrep = 16 halves readers-per-line on the hot mailbox lines (MALL bank
    // queueing is a V_eff component); auto-falls-back if ws is small.
    int nrep = (int)(ws_size / REP_BYTES);
    if (nrep > 16) nrep = 16;
    if (nrep < 1) nrep = 1;

    lstm_persist<<<dim3(NBLK), dim3(NTHR), 0, stream>>>(
        x, Wih0, Whh0, bih0, bhh0, Wih12, Whh12, bih12, bhh12,
        Wres, bres, out, ws, nrep);
}

// Round 9
// 11726.350 us; speedup vs baseline: 1.3257x; 1.3257x over previous
//
#include <hip/hip_runtime.h>

#define HSZ 1024
#define TSTEPS 4096
#define NBLK 256
#define NTHR 256   // 4 waves/block x 256 blocks = 1024 waves == HSZ units
#define HV (HSZ / 4)
#define REP_BYTES 24576  // one replica: [2 parity][3 array][1024 tagged dwords]

typedef _Float16 half2v __attribute__((ext_vector_type(2)));
typedef unsigned long long ull;

#if __has_builtin(__builtin_amdgcn_fdot2)
#define FDOT2(a, b, c) __builtin_amdgcn_fdot2((a), (b), (c), false)
#else
__device__ __forceinline__ float FDOT2(half2v a, half2v b, float c) {
    return c + (float)a.x * (float)b.x + (float)a.y * (float)b.y;
}
#endif

__device__ __forceinline__ int f2i(float f) { int i; __builtin_memcpy(&i, &f, 4); return i; }
__device__ __forceinline__ float i2f(int i) { float f; __builtin_memcpy(&f, &i, 4); return f; }

// ---- DPP wave reduction: full 64-lane sum lands on lane 63 (VALU-rate) ----
template <int CTRL, int RM>
__device__ __forceinline__ float dpp_acc(float v) {
    int t = __builtin_amdgcn_update_dpp(0, f2i(v), CTRL, RM, 0xf, true);
    return v + i2f(t);
}
__device__ __forceinline__ float wave_sum63(float v) {
    v = dpp_acc<0x111, 0xf>(v);  // row_shr:1
    v = dpp_acc<0x112, 0xf>(v);  // row_shr:2
    v = dpp_acc<0x114, 0xf>(v);  // row_shr:4
    v = dpp_acc<0x118, 0xf>(v);  // row_shr:8  -> lane15/31/47/63 hold row sums
    v = dpp_acc<0x142, 0xa>(v);  // row_bcast:15 (rows 1,3 only)
    v = dpp_acc<0x143, 0xc>(v);  // row_bcast:31 (rows 2,3 only) -> lane63 = total
    return v;
}
// reduce + broadcast to ALL lanes (readlane of the lane-63 total)
__device__ __forceinline__ float wave_sum_bcast(float v) {
    return i2f(__builtin_amdgcn_readlane(f2i(wave_sum63(v)), 63));
}

__device__ __forceinline__ float sigm(float x) { return 1.0f / (1.0f + __expf(-x)); }
__device__ __forceinline__ float tanh_fast(float x) {
    const float e = __expf(2.0f * x);
    return 1.0f - 2.0f / (e + 1.0f);
}

// ---- agent-coherent (L3-level) accesses, no cache fences ----
__device__ __forceinline__ ull ld_coh64(const ull* p) {
    return __hip_atomic_load(p, __ATOMIC_RELAXED, __HIP_MEMORY_SCOPE_AGENT);
}
__device__ __forceinline__ void st_coh32(unsigned* p, unsigned v) {
    __hip_atomic_store(p, v, __ATOMIC_RELAXED, __HIP_MEMORY_SCOPE_AGENT);
}

__device__ __forceinline__ unsigned f16bits(float v) {
    _Float16 h = (_Float16)v;
    unsigned short b;
    __builtin_memcpy(&b, &h, 2);
    return (unsigned)b;
}

// Pin packed-f16 weight into a VGPR (prevents load re-sinking).
#define PINH(h) asm volatile("" : "+v"(h))

// f32->half2 (init path, RNE per element)
__device__ __forceinline__ half2v cvt2(float a, float b) {
    half2v r; r.x = (_Float16)a; r.y = (_Float16)b; return r;
}

__device__ __forceinline__ half2v bits_to_h2(unsigned v) {
    half2v h; __builtin_memcpy(&h, &v, 4); return h;
}

// strip two 16-bit tags from a tagged-dword pair -> packed f16 pair (1 v_perm)
__device__ __forceinline__ unsigned pack_payload(ull q) {
#if __has_builtin(__builtin_amdgcn_perm)
    return __builtin_amdgcn_perm((unsigned)(q >> 32), (unsigned)q, 0x05040100u);
#else
    return ((unsigned)q & 0xFFFFu) | ((unsigned)(q >> 32) << 16);
#endif
}

// ---- per-WAVE register-direct poll (champion geometry): 8 coalesced b64
// loads/lane cover one 1024-unit tagged array. Split-phase: issued one phase
// ahead, checked one phase later (flight hidden under compute). ----
struct PollA { ull q[8]; };

__device__ __forceinline__ PollA poll_issueA(const ull* A, int lane) {
    PollA p;
#pragma unroll
    for (int i = 0; i < 4; ++i) {
        p.q[2 * i]     = ld_coh64(A + 2 * lane + 128 * i);
        p.q[2 * i + 1] = ld_coh64(A + 2 * lane + 128 * i + 1);
    }
    return p;
}

// Selective-lane retry; retries 1-3 immediate (the marginal check that defines
// the period sits on this grid -- sleep wake-latency would add straight to T),
// sleep-backoff from the 4th retry to bound pathological congestion.
__device__ __forceinline__ void poll_completeA(PollA& p, const ull* A,
                                               unsigned e, int lane, half2v* hf) {
    const ull K = ((ull)e << 16) | ((ull)e << 48);
    ull bad = 0;
#pragma unroll
    for (int j = 0; j < 8; ++j) bad |= (p.q[j] ^ K);
    bad &= 0xFFFF0000FFFF0000ull;
    int tries = 0;
    while (!__all(bad == 0)) {
        if (tries >= 3) __builtin_amdgcn_s_sleep(2);
        ++tries;
        if (bad) {  // divergent: only stale lanes reload
#pragma unroll
            for (int i = 0; i < 4; ++i) {
                p.q[2 * i]     = ld_coh64(A + 2 * lane + 128 * i);
                p.q[2 * i + 1] = ld_coh64(A + 2 * lane + 128 * i + 1);
            }
            bad = 0;
#pragma unroll
            for (int j = 0; j < 8; ++j) bad |= (p.q[j] ^ K);
            bad &= 0xFFFF0000FFFF0000ull;
        }
    }
#pragma unroll
    for (int j = 0; j < 8; ++j) hf[j] = bits_to_h2(pack_payload(p.q[j]));
}

__global__ void __launch_bounds__(NTHR, 1) lstm_persist(
    const float* __restrict__ x,
    const float* __restrict__ Wih0, const float* __restrict__ Whh0,
    const float* __restrict__ bih0, const float* __restrict__ bhh0,
    const float* __restrict__ Wih12, const float* __restrict__ Whh12,
    const float* __restrict__ bih12, const float* __restrict__ bhh12,
    const float* __restrict__ Wres, const float* __restrict__ bres,
    float* __restrict__ out, float* __restrict__ ws_f, int nrep)
{
    char* wsb = (char*)ws_f;
    const int lane = threadIdx.x & 63;
    const int u = blockIdx.x * (NTHR / 64) + (threadIdx.x >> 6);  // hidden unit
    const int tid = threadIdx.x;

    // ---- init: parity 1 of every replica = tag 0, value 0 ----
    {
        const int gid = blockIdx.x * NTHR + tid;
        if (gid < nrep * 3072) {
            const int rep = gid / 3072, d = gid % 3072;
            st_coh32((unsigned*)(wsb + rep * REP_BYTES) + 3072 + d, 0u);
        }
    }

    // ---- per-wave scalar constants ----
    float b0[4], b1[4], b2[4], wx0a[4], wx0b[4];
#pragma unroll
    for (int g = 0; g < 4; ++g) {
        const int r = g * HSZ + u;
        b0[g] = bih0[r] + bhh0[r];
        b1[g] = bih12[r] + bhh12[r];
        b2[g] = bih12[4 * HSZ + r] + bhh12[4 * HSZ + r];
        wx0a[g] = Wih0[2 * r];
        wx0b[g] = Wih0[2 * r + 1];
    }

    // ---- register-resident f16 weights: 20 rows x 1024 -> 160 half2/lane ----
    const float4* Whh0v = (const float4*)Whh0;
    const float4* Wih1v = (const float4*)Wih12;
    const float4* Whh1v = (const float4*)Whh12;
    const float4* Wih2v = (const float4*)(Wih12 + 4 * HSZ * HSZ);
    const float4* Whh2v = (const float4*)(Whh12 + 4 * HSZ * HSZ);

    half2v w0h[4][8], wi1h[4][8], wh1h[4][8], wi2h[4][8], wh2h[4][8];
#pragma unroll
    for (int g = 0; g < 4; ++g) {
        const size_t r = (size_t)(g * HSZ + u) * HV + lane;
#pragma unroll
        for (int i = 0; i < 4; ++i) {
            float4 t;
            t = Whh0v[r + 64 * i];  w0h[g][2*i] = cvt2(t.x,t.y);  w0h[g][2*i+1] = cvt2(t.z,t.w);
            t = Wih1v[r + 64 * i];  wi1h[g][2*i] = cvt2(t.x,t.y); wi1h[g][2*i+1] = cvt2(t.z,t.w);
            t = Whh1v[r + 64 * i];  wh1h[g][2*i] = cvt2(t.x,t.y); wh1h[g][2*i+1] = cvt2(t.z,t.w);
            t = Wih2v[r + 64 * i];  wi2h[g][2*i] = cvt2(t.x,t.y); wi2h[g][2*i+1] = cvt2(t.z,t.w);
            t = Whh2v[r + 64 * i];  wh2h[g][2*i] = cvt2(t.x,t.y); wh2h[g][2*i+1] = cvt2(t.z,t.w);
        }
    }
#pragma unroll
    for (int g = 0; g < 4; ++g)
#pragma unroll
        for (int j = 0; j < 8; ++j) {
            PINH(w0h[g][j]); PINH(wi1h[g][j]); PINH(wh1h[g][j]);
            PINH(wi2h[g][j]); PINH(wh2h[g][j]);
        }

    // head weights as f16 (distributed head: every wave serves 4 of 4096 steps)
    half2v wresh[8];
    {
        const float4* wr = (const float4*)Wres;
#pragma unroll
        for (int i = 0; i < 4; ++i) {
            float4 t = wr[lane + 64 * i];
            wresh[2*i] = cvt2(t.x, t.y); wresh[2*i+1] = cvt2(t.z, t.w);
        }
    }
    const float bres0 = bres[0];

    // Drain init stores so no late init write can clobber a live tagged word.
    asm volatile("s_waitcnt vmcnt(0)" ::: "memory");
    __syncthreads();

    const ull* Tmyq = (const ull*)(wsb + (blockIdx.x % nrep) * REP_BYTES);

    float c0 = 0.0f, c1 = 0.0f, c2 = 0.0f;  // wave-uniform (all lanes)

    // Champion wavefront pipeline, split-phase polls (uniform slack geometry):
    //   iter k: check pq0 -> issue pq1 -> L0 -> pub h0
    //           -> check pq1 -> issue pq2 -> L1 -> pub h1
    //           -> check pq2 -> issue pq0(next parity) -> L2 -> pub h2 -> head?
    // Publish = readlane-broadcast gates -> wave-uniform activations ->
    // ONE parallel store (lane r stores replica r) -- no serial fan-out.
    PollA pq0 = poll_issueA(Tmyq + 1536, lane);  // k=0 reads parity 1, array 0

    for (int k = 0; k <= TSTEPS + 2; ++k) {
        const int wp = k & 1, rp = wp ^ 1;
        const unsigned e = (unsigned)k;
        const ull* Trp = Tmyq + rp * 1536;
        const ull* Tnx = Tmyq + wp * 1536;  // next iter's read parity
        const bool pub = (k <= TSTEPS + 1);
        const unsigned tg = (unsigned)(k + 1) << 16;

        // prefetch x before the poll-wait (hides the load latency)
        float x0 = 0.0f, x1 = 0.0f;
        if (k < TSTEPS) { x0 = x[2 * k]; x1 = x[2 * k + 1]; }

        // ================= layer 0 =================
        half2v haf[8];
        poll_completeA(pq0, Trp, e, lane, haf);
        PollA pq1 = poll_issueA(Trp + 512, lane);  // in flight during L0

        float h0v = 0.0f;
        if (k < TSTEPS) {
            float acc[4];
#pragma unroll
            for (int g = 0; g < 4; ++g) {
                float a = 0.0f;
#pragma unroll
                for (int j = 0; j < 8; ++j) a = FDOT2(w0h[g][j], haf[j], a);
                acc[g] = a;
            }
#pragma unroll
            for (int g = 0; g < 4; ++g) acc[g] = wave_sum_bcast(acc[g]);
            const float ig = sigm(acc[0] + b0[0] + wx0a[0] * x0 + wx0b[0] * x1);
            const float fg = sigm(acc[1] + b0[1] + wx0a[1] * x0 + wx0b[1] * x1);
            const float gg = tanh_fast(acc[2] + b0[2] + wx0a[2] * x0 + wx0b[2] * x1);
            const float og = sigm(acc[3] + b0[3] + wx0a[3] * x0 + wx0b[3] * x1);
            c0 = fg * c0 + ig * gg;
            h0v = og * tanh_fast(c0);
        }
        if (pub && lane < nrep) {
            const unsigned wb = tg | f16bits(h0v);
            st_coh32((unsigned*)(wsb + lane * REP_BYTES) + wp * 3072 + u, wb);
        }

        // ================= layer 1 =================
        half2v hbf[8];
        poll_completeA(pq1, Trp + 512, e, lane, hbf);
        PollA pq2 = poll_issueA(Trp + 1024, lane);  // in flight during L1

        float h1v = 0.0f;
        if (k >= 1 && k <= TSTEPS) {
            float acc[4];
#pragma unroll
            for (int g = 0; g < 4; ++g) {
                float a = 0.0f;
#pragma unroll
                for (int j = 0; j < 8; ++j) {
                    a = FDOT2(wi1h[g][j], haf[j], a);
                    a = FDOT2(wh1h[g][j], hbf[j], a);
                }
                acc[g] = a;
            }
#pragma unroll
            for (int g = 0; g < 4; ++g) acc[g] = wave_sum_bcast(acc[g]);
            const float ig = sigm(acc[0] + b1[0]);
            const float fg = sigm(acc[1] + b1[1]);
            const float gg = tanh_fast(acc[2] + b1[2]);
            const float og = sigm(acc[3] + b1[3]);
            c1 = fg * c1 + ig * gg;
            h1v = og * tanh_fast(c1);
        }
        if (pub && lane < nrep) {
            const unsigned wb = tg | f16bits(h1v);
            st_coh32((unsigned*)(wsb + lane * REP_BYTES) + wp * 3072 + 1024 + u, wb);
        }

        // ================= layer 2 =================
        half2v hcf[8];
        poll_completeA(pq2, Trp + 1024, e, lane, hcf);
        pq0 = poll_issueA(Tnx, lane);  // next iter's array 0, in flight during L2

        float h2v = 0.0f;
        if (k >= 2 && k <= TSTEPS + 1) {
            float acc[4];
#pragma unroll
            for (int g = 0; g < 4; ++g) {
                float a = 0.0f;
#pragma unroll
                for (int j = 0; j < 8; ++j) {
                    a = FDOT2(wi2h[g][j], hbf[j], a);
                    a = FDOT2(wh2h[g][j], hcf[j], a);
                }
                acc[g] = a;
            }
#pragma unroll
            for (int g = 0; g < 4; ++g) acc[g] = wave_sum_bcast(acc[g]);
            const float ig = sigm(acc[0] + b2[0]);
            const float fg = sigm(acc[1] + b2[1]);
            const float gg = tanh_fast(acc[2] + b2[2]);
            const float og = sigm(acc[3] + b2[3]);
            c2 = fg * c2 + ig * gg;
            h2v = og * tanh_fast(c2);
        }
        if (pub && lane < nrep) {
            const unsigned wb = tg | f16bits(h2v);
            st_coh32((unsigned*)(wsb + lane * REP_BYTES) + wp * 3072 + 2048 + u, wb);
        }

        // ===== distributed head: out[t] served by wave t&1023 (4 per wave
        // total; wave-uniform branch, no permanent straggler) =====
        if (k >= 3 && ((k - 3) & (HSZ - 1)) == u) {
            float a = 0.0f;
#pragma unroll
            for (int j = 0; j < 8; ++j) a = FDOT2(wresh[j], hcf[j], a);
            a = wave_sum63(a);
            if (lane == 63) out[k - 3] = sigm(a + bres0);
        }
    }
}

extern "C" void kernel_launch(void* const* d_in, const int* in_sizes, int n_in,
                              void* d_out, int out_size, void* d_ws, size_t ws_size,
                              hipStream_t stream) {
    const float* x     = (const float*)d_in[0];
    const float* Wih0  = (const float*)d_in[1];
    const float* Whh0  = (const float*)d_in[2];
    const float* bih0  = (const float*)d_in[3];
    const float* bhh0  = (const float*)d_in[4];
    const float* Wih12 = (const float*)d_in[5];
    const float* Whh12 = (const float*)d_in[6];
    const float* bih12 = (const float*)d_in[7];
    const float* bhh12 = (const float*)d_in[8];
    const float* Wres  = (const float*)d_in[9];
    const float* bres  = (const float*)d_in[10];
    float* out = (float*)d_out;
    float* ws  = (float*)d_ws;

    // nrep = 8 (R8's 16 regressed: doubled publish fan-out + mailbox footprint)
    int nrep = (int)(ws_size / REP_BYTES);
    if (nrep > 8) nrep = 8;
    if (nrep < 1) nrep = 1;

    lstm_persist<<<dim3(NBLK), dim3(NTHR), 0, stream>>>(
        x, Wih0, Whh0, bih0, bhh0, Wih12, Whh12, bih12, bhh12,
        Wres, bres, out, ws, nrep);
}